// Round 6
// baseline (244.147 us; speedup 1.0000x reference)
//
#include <hip/hip_runtime.h>
#include <hip/hip_cooperative_groups.h>

namespace cg = cooperative_groups;

#define CC 256
#define EE 128
#define BB 8
#define NN 3136
#define NN4 784      // NN / 4 (float4 per row)
#define T4 16        // float4 per i-tile (64 spatial positions)
#define NTILES 49    // NN4 / T4
#define NFUSED (BB * NTILES)   // 392 blocks — every block is a fused (b,tile) block

__device__ __forceinline__ float waveReduceSum(float v) {
    #pragma unroll
    for (int off = 32; off > 0; off >>= 1) v += __shfl_down(v, off, 64);
    return v;
}

// ws layout (floats): xbar[2048]@0, gexp[2048]@2048, A[256]@4096, cst@4352,
//                     h[256]@4368, M[256*256]@4624, partials[392*256]@70160
__global__ void __launch_bounds__(256, 2) k_all(
        const float* __restrict__ x,
        const float* __restrict__ Wq, const float* __restrict__ bq,
        const float* __restrict__ Wk, const float* __restrict__ bk,
        const float* __restrict__ Wv, const float* __restrict__ bv,
        const float* __restrict__ Wcat, const float* __restrict__ Wexp,
        const float* __restrict__ bexp, float* __restrict__ out,
        float* __restrict__ ws) {
    cg::grid_group grid = cg::this_grid();

    float* xbar     = ws;
    float* gexp     = ws + 2048;
    float* Ag       = ws + 4096;
    float* cst      = ws + 4352;
    float* hg       = ws + 4368;
    float* Mg       = ws + 4624;
    float* partials = ws + 70160;

    __shared__ float partc[CC][T4 + 1];
    __shared__ float A_s[CC];
    __shared__ float g_s[CC];
    __shared__ float be_s[CC];
    __shared__ float4 part4[16][16];
    __shared__ float4 s_s[16];

    const int blk = blockIdx.x;
    const int tid = threadIdx.x;
    const int i4l = tid & 15;          // float4 slot within tile
    const int cgi = tid >> 4;          // c-group (16 channels each)
    const int b = blk / NTILES;
    const int tile = blk - b * NTILES;
    const float4* x4 = (const float4*)x + (size_t)b * CC * NN4
                       + (size_t)tile * T4 + i4l;

    // ---- P0: read x ONCE into registers; per-channel tile partials ----
    float4 xc[16];
    #pragma unroll
    for (int j = 0; j < 16; j++) {
        int c = cgi * 16 + j;
        float4 v = x4[(size_t)c * NN4];
        xc[j] = v;
        partc[c][i4l] = (v.x + v.y) + (v.z + v.w);
    }
    __syncthreads();
    {
        float sum = 0.f;
        #pragma unroll
        for (int i = 0; i < T4; i++) sum += partc[tid][i];
        partials[blk * CC + tid] = sum;
    }
    grid.sync();

    // ---- P1: blocks 0..7 xbar reduce; 8..263 M rows + h; 264 A/cst ----
    if (blk < BB) {
        float s = 0.f;
        #pragma unroll 7
        for (int t = 0; t < NTILES; t++)
            s += partials[(blk * NTILES + t) * CC + tid];
        xbar[blk * CC + tid] = s * (1.0f / NN);
    } else if (blk < BB + CC) {
        int r = blk - BB;              // M row r: M[r,k] = sum_e Wexp[r,e]*Wv[e,k]
        const float* wer = Wexp + r * EE;
        float m = 0.f;
        #pragma unroll 8
        for (int e = 0; e < EE; e++) m += wer[e] * Wv[e * CC + tid];
        Mg[r * CC + tid] = m;
        if (tid < 64) {
            float hp = wer[tid] * bv[tid] + wer[tid + 64] * bv[tid + 64];
            hp = waveReduceSum(hp);
            if (tid == 0) hg[r] = hp;
        }
    } else if (blk == BB + CC) {
        float a = 0.f;
        #pragma unroll 8
        for (int e = 0; e < EE; e++)
            a += Wcat[e] * Wq[e * CC + tid] + Wcat[EE + e] * Wk[e * CC + tid];
        Ag[tid] = a;
        if (tid < 64) {
            float cp = Wcat[tid] * bq[tid] + Wcat[tid + 64] * bq[tid + 64]
                     + Wcat[EE + tid] * bk[tid] + Wcat[EE + tid + 64] * bk[tid + 64];
            cp = waveReduceSum(cp);
            if (tid == 0) cst[0] = cp;
        }
    }
    grid.sync();

    // ---- P2: gexp[b,c] = M[c,:]·xbar[b,:] + h[c]  (2048 dots, 1568 waves) ----
    {
        int w = tid >> 6, lane = tid & 63;
        int gw = blk * 4 + w;                          // 0..1567
        #pragma unroll
        for (int rep = 0; rep < 2; rep++) {
            int d = gw + rep * 1568;
            if (d < 2048) {
                int b2 = d >> 8, c2 = d & 255;
                const float* Mr = Mg + c2 * CC;
                const float* xb = xbar + b2 * CC;
                float acc = Mr[lane]       * xb[lane]
                          + Mr[lane + 64]  * xb[lane + 64]
                          + Mr[lane + 128] * xb[lane + 128]
                          + Mr[lane + 192] * xb[lane + 192];
                acc = waveReduceSum(acc);
                if (lane == 0) gexp[d] = acc + hg[c2];
            }
        }
    }
    grid.sync();

    // ---- P3: s = relu(A·x + cst); out = x + s*g + bexp (x from registers) ----
    A_s[tid]  = Ag[tid];
    g_s[tid]  = gexp[b * CC + tid];
    be_s[tid] = bexp[tid];
    __syncthreads();
    float4 acc = make_float4(0.f, 0.f, 0.f, 0.f);
    #pragma unroll
    for (int j = 0; j < 16; j++) {
        int c = cgi * 16 + j;
        float a = A_s[c];
        float4 v = xc[j];
        acc.x = fmaf(a, v.x, acc.x);
        acc.y = fmaf(a, v.y, acc.y);
        acc.z = fmaf(a, v.z, acc.z);
        acc.w = fmaf(a, v.w, acc.w);
    }
    part4[cgi][i4l] = acc;
    __syncthreads();
    if (tid < 16) {
        float4 sum = part4[0][tid];
        #pragma unroll
        for (int g = 1; g < 16; g++) {
            float4 p = part4[g][tid];
            sum.x += p.x; sum.y += p.y; sum.z += p.z; sum.w += p.w;
        }
        float cv = cst[0];
        float4 s;
        s.x = fmaxf(sum.x + cv, 0.f);
        s.y = fmaxf(sum.y + cv, 0.f);
        s.z = fmaxf(sum.z + cv, 0.f);
        s.w = fmaxf(sum.w + cv, 0.f);
        s_s[tid] = s;
    }
    __syncthreads();
    {
        float4 sv = s_s[i4l];
        float4* o4 = (float4*)out + (size_t)b * CC * NN4 + (size_t)tile * T4 + i4l;
        #pragma unroll
        for (int j = 0; j < 16; j++) {
            int c = cgi * 16 + j;
            float g  = g_s[c];
            float be = be_s[c];
            float4 xv = xc[j];
            float4 o;
            o.x = fmaf(sv.x, g, xv.x) + be;
            o.y = fmaf(sv.y, g, xv.y) + be;
            o.z = fmaf(sv.z, g, xv.z) + be;
            o.w = fmaf(sv.w, g, xv.w) + be;
            o4[(size_t)c * NN4] = o;
        }
    }
}

// ---------------- fallback path (proven round-4 kernels) ----------------
__global__ void k_xbar(const float* __restrict__ x, float* __restrict__ xbar) {
    int row = blockIdx.x;
    int tid = threadIdx.x;
    const float4* xr = (const float4*)(x + (size_t)row * NN);
    float acc = 0.f;
    for (int i = tid; i < NN4; i += 256) {
        float4 v = xr[i];
        acc += (v.x + v.y) + (v.z + v.w);
    }
    acc = waveReduceSum(acc);
    __shared__ float red[4];
    int wid = tid >> 6, lane = tid & 63;
    if (lane == 0) red[wid] = acc;
    __syncthreads();
    if (tid == 0) xbar[row] = (red[0] + red[1] + red[2] + red[3]) * (1.0f / NN);
}

__global__ void k_vbar(const float* __restrict__ xbar, const float* __restrict__ Wv,
                       const float* __restrict__ bv, float* __restrict__ vbar) {
    int w = threadIdx.x >> 6, lane = threadIdx.x & 63;
    int d = blockIdx.x * 4 + w;
    int b = d >> 7, e = d & 127;
    const float* wr = Wv + e * CC;
    const float* xb = xbar + b * CC;
    float acc = wr[lane]       * xb[lane]
              + wr[lane + 64]  * xb[lane + 64]
              + wr[lane + 128] * xb[lane + 128]
              + wr[lane + 192] * xb[lane + 192];
    acc = waveReduceSum(acc);
    if (lane == 0) vbar[d] = acc + bv[e];
}

__global__ void k_gexp(const float* __restrict__ vbar, const float* __restrict__ Wexp,
                       const float* __restrict__ Wq, const float* __restrict__ bq,
                       const float* __restrict__ Wk, const float* __restrict__ bk,
                       const float* __restrict__ Wcat,
                       float* __restrict__ gexp, float* __restrict__ Aout,
                       float* __restrict__ cst) {
    int tid = threadIdx.x;
    if (blockIdx.x == 512) {
        float a = 0.f;
        #pragma unroll 8
        for (int e = 0; e < EE; e++)
            a += Wcat[e] * Wq[e * CC + tid] + Wcat[EE + e] * Wk[e * CC + tid];
        Aout[tid] = a;
        if (tid < 64) {
            float cp = Wcat[tid] * bq[tid] + Wcat[tid + 64] * bq[tid + 64]
                     + Wcat[EE + tid] * bk[tid] + Wcat[EE + tid + 64] * bk[tid + 64];
            cp = waveReduceSum(cp);
            if (tid == 0) cst[0] = cp;
        }
        return;
    }
    int w = tid >> 6, lane = tid & 63;
    int d = blockIdx.x * 4 + w;
    int b = d >> 8, c = d & 255;
    const float* we = Wexp + c * EE;
    const float* vb = vbar + b * EE;
    float acc = we[lane] * vb[lane] + we[lane + 64] * vb[lane + 64];
    acc = waveReduceSum(acc);
    if (lane == 0) gexp[d] = acc;
}

#define FT4 8
#define FNTILES 98
__global__ void __launch_bounds__(256) k_fused(
        const float* __restrict__ x, const float* __restrict__ A,
        const float* __restrict__ cst, const float* __restrict__ gexp,
        const float* __restrict__ bexp, float* __restrict__ out) {
    int b = blockIdx.x / FNTILES;
    int tile = blockIdx.x - b * FNTILES;
    int tid = threadIdx.x;
    int i4l = tid & 7, cg = tid >> 3;

    __shared__ float A_s[CC];
    __shared__ float g_s[CC];
    __shared__ float be_s[CC];
    __shared__ float4 part[32][8];
    __shared__ float4 s_s[8];

    A_s[tid]  = A[tid];
    g_s[tid]  = gexp[b * CC + tid];
    be_s[tid] = bexp[tid];
    __syncthreads();

    const float4* x4 = (const float4*)x + (size_t)b * CC * NN4 + tile * FT4;
    float4*       o4 = (float4*)out     + (size_t)b * CC * NN4 + tile * FT4;

    float4 xc[8];
    float4 acc = make_float4(0.f, 0.f, 0.f, 0.f);
    #pragma unroll
    for (int j = 0; j < 8; j++) {
        int c = cg * 8 + j;
        float4 v = x4[(size_t)c * NN4 + i4l];
        xc[j] = v;
        float a = A_s[c];
        acc.x = fmaf(a, v.x, acc.x);
        acc.y = fmaf(a, v.y, acc.y);
        acc.z = fmaf(a, v.z, acc.z);
        acc.w = fmaf(a, v.w, acc.w);
    }
    part[cg][i4l] = acc;
    __syncthreads();
    if (tid < 8) {
        float4 sum = part[0][tid];
        #pragma unroll
        for (int g = 1; g < 32; g++) {
            float4 p = part[g][tid];
            sum.x += p.x; sum.y += p.y; sum.z += p.z; sum.w += p.w;
        }
        float cv = cst[0];
        float4 s;
        s.x = fmaxf(sum.x + cv, 0.f);
        s.y = fmaxf(sum.y + cv, 0.f);
        s.z = fmaxf(sum.z + cv, 0.f);
        s.w = fmaxf(sum.w + cv, 0.f);
        s_s[tid] = s;
    }
    __syncthreads();
    float4 sv = s_s[i4l];
    #pragma unroll
    for (int j = 0; j < 8; j++) {
        int c = cg * 8 + j;
        float g  = g_s[c];
        float be = be_s[c];
        float4 xv = xc[j];
        float4 o;
        o.x = fmaf(sv.x, g, xv.x) + be;
        o.y = fmaf(sv.y, g, xv.y) + be;
        o.z = fmaf(sv.z, g, xv.z) + be;
        o.w = fmaf(sv.w, g, xv.w) + be;
        o4[(size_t)c * NN4 + i4l] = o;
    }
}

extern "C" void kernel_launch(void* const* d_in, const int* in_sizes, int n_in,
                              void* d_out, int out_size, void* d_ws, size_t ws_size,
                              hipStream_t stream) {
    const float* x    = (const float*)d_in[0];
    const float* Wq   = (const float*)d_in[1];
    const float* bq   = (const float*)d_in[2];
    const float* Wk   = (const float*)d_in[3];
    const float* bk   = (const float*)d_in[4];
    const float* Wv   = (const float*)d_in[5];
    const float* bv   = (const float*)d_in[6];
    const float* Wcat = (const float*)d_in[7];
    const float* Wexp = (const float*)d_in[8];
    const float* bexp = (const float*)d_in[9];
    float* out = (float*)d_out;
    float* ws  = (float*)d_ws;

    void* args[] = {
        (void*)&x, (void*)&Wq, (void*)&bq, (void*)&Wk, (void*)&bk,
        (void*)&Wv, (void*)&bv, (void*)&Wcat, (void*)&Wexp, (void*)&bexp,
        (void*)&out, (void*)&ws
    };
    hipError_t err = hipLaunchCooperativeKernel((const void*)k_all, dim3(NFUSED),
                                                dim3(256), args, 0, stream);
    if (err != hipSuccess) {
        // fallback: proven 4-kernel path
        float* xbar = ws;
        float* gexp = ws + 2048;
        float* A    = ws + 4096;
        float* cst  = ws + 4352;
        float* vbar = ws + 4624;
        k_xbar<<<BB * CC, 256, 0, stream>>>(x, xbar);
        k_vbar<<<256, 256, 0, stream>>>(xbar, Wv, bv, vbar);
        k_gexp<<<513, 256, 0, stream>>>(vbar, Wexp, Wq, bq, Wk, bk, Wcat, gexp, A, cst);
        k_fused<<<BB * FNTILES, 256, 0, stream>>>(x, A, cst, gexp, bexp, out);
    }
}

// Round 7
// 109.944 us; speedup vs baseline: 2.2206x; 2.2206x over previous
//
#include <hip/hip_runtime.h>

#define CC 256
#define EE 128
#define BB 8
#define NN 3136
#define NN4 784      // NN / 4 (float4 per row)
#define T4 8         // float4 per i-tile (32 spatial positions)
#define NTILES 98    // NN4 / T4

__device__ __forceinline__ float waveReduceSum(float v) {
    #pragma unroll
    for (int off = 32; off > 0; off >>= 1) v += __shfl_down(v, off, 64);
    return v;
}

// k1: blocks 0..2047   -> xbar[row] = mean_i x[row, i]        (HBM pass over x)
//     blocks 2048..2303 -> M[r,k] = sum_e Wexp[r,e]*Wv[e,k];  h[r] = Wexp[r,:]·bv
//     block 2304        -> A[c] = Wcat[:E]·Wq[:,c] + Wcat[E:]·Wk[:,c];  cst
__global__ void __launch_bounds__(256) k1(
        const float* __restrict__ x,
        const float* __restrict__ Wq, const float* __restrict__ bq,
        const float* __restrict__ Wk, const float* __restrict__ bk,
        const float* __restrict__ Wv, const float* __restrict__ bv,
        const float* __restrict__ Wcat, const float* __restrict__ Wexp,
        float* __restrict__ xbar, float* __restrict__ Mg, float* __restrict__ hg,
        float* __restrict__ Ag, float* __restrict__ cst) {
    const int blk = blockIdx.x;
    const int tid = threadIdx.x;
    if (blk < BB * CC) {
        const float4* xr = (const float4*)(x + (size_t)blk * NN);
        float acc = 0.f;
        for (int i = tid; i < NN4; i += 256) {
            float4 v = xr[i];
            acc += (v.x + v.y) + (v.z + v.w);
        }
        acc = waveReduceSum(acc);
        __shared__ float red[4];
        int wid = tid >> 6, lane = tid & 63;
        if (lane == 0) red[wid] = acc;
        __syncthreads();
        if (tid == 0) xbar[blk] = (red[0] + red[1] + red[2] + red[3]) * (1.0f / NN);
    } else if (blk < BB * CC + CC) {
        int r = blk - BB * CC;
        __shared__ float we_s[EE];
        if (tid < EE) we_s[tid] = Wexp[r * EE + tid];
        __syncthreads();
        float m = 0.f;
        #pragma unroll 8
        for (int e = 0; e < EE; e++) m += we_s[e] * Wv[e * CC + tid];
        Mg[r * CC + tid] = m;
        if (tid < 64) {
            float hp = we_s[tid] * bv[tid] + we_s[tid + 64] * bv[tid + 64];
            hp = waveReduceSum(hp);
            if (tid == 0) hg[r] = hp;
        }
    } else {
        float a = 0.f;
        #pragma unroll 8
        for (int e = 0; e < EE; e++)
            a += Wcat[e] * Wq[e * CC + tid] + Wcat[EE + e] * Wk[e * CC + tid];
        Ag[tid] = a;
        if (tid < 64) {
            float cp = Wcat[tid] * bq[tid] + Wcat[tid + 64] * bq[tid + 64]
                     + Wcat[EE + tid] * bk[tid] + Wcat[EE + tid + 64] * bk[tid + 64];
            cp = waveReduceSum(cp);
            if (tid == 0) cst[0] = cp;
        }
    }
}

// k2: gexp[b,c] = M[c,:]·xbar[b,:] + h[c]   (2048 wave-dots, len 256)
__global__ void __launch_bounds__(256) k2(
        const float* __restrict__ xbar, const float* __restrict__ Mg,
        const float* __restrict__ hg, float* __restrict__ gexp) {
    int w = threadIdx.x >> 6, lane = threadIdx.x & 63;
    int d = blockIdx.x * 4 + w;        // 0..2047
    int b = d >> 8, c = d & 255;
    const float* Mr = Mg + c * CC;
    const float* xb = xbar + b * CC;
    float acc = Mr[lane]       * xb[lane]
              + Mr[lane + 64]  * xb[lane + 64]
              + Mr[lane + 128] * xb[lane + 128]
              + Mr[lane + 192] * xb[lane + 192];
    acc = waveReduceSum(acc);
    if (lane == 0) gexp[d] = acc + hg[c];
}

// k3: fused s + out. block = (b, tile of 8 float4 = 32 spatial positions).
// Each thread owns 8 channels at one float4 slot; x cached in registers.
// phase A: s[i] = relu(sum_c A[c]*x[b,c,i] + cst)
// phase B: out[b,c,i] = x[b,c,i] + s[i]*gexp[b,c] + bexp[c]
__global__ void __launch_bounds__(256) k3(
        const float* __restrict__ x, const float* __restrict__ A,
        const float* __restrict__ cst, const float* __restrict__ gexp,
        const float* __restrict__ bexp, float* __restrict__ out) {
    int b = blockIdx.x / NTILES;
    int tile = blockIdx.x - b * NTILES;
    int tid = threadIdx.x;
    int i4l = tid & 7, cg = tid >> 3;   // 8 i-slots x 32 c-groups (8 ch each)

    __shared__ float A_s[CC];
    __shared__ float g_s[CC];
    __shared__ float be_s[CC];
    __shared__ float4 part[32][8];
    __shared__ float4 s_s[8];

    A_s[tid]  = A[tid];
    g_s[tid]  = gexp[b * CC + tid];
    be_s[tid] = bexp[tid];
    __syncthreads();

    const float4* x4 = (const float4*)x + (size_t)b * CC * NN4 + tile * T4;
    float4*       o4 = (float4*)out     + (size_t)b * CC * NN4 + tile * T4;

    float4 xc[8];
    float4 acc = make_float4(0.f, 0.f, 0.f, 0.f);
    #pragma unroll
    for (int j = 0; j < 8; j++) {
        int c = cg * 8 + j;
        float4 v = x4[(size_t)c * NN4 + i4l];
        xc[j] = v;
        float a = A_s[c];
        acc.x = fmaf(a, v.x, acc.x);
        acc.y = fmaf(a, v.y, acc.y);
        acc.z = fmaf(a, v.z, acc.z);
        acc.w = fmaf(a, v.w, acc.w);
    }
    part[cg][i4l] = acc;
    __syncthreads();
    if (tid < 8) {
        float4 sum = part[0][tid];
        #pragma unroll
        for (int g = 1; g < 32; g++) {
            float4 p = part[g][tid];
            sum.x += p.x; sum.y += p.y; sum.z += p.z; sum.w += p.w;
        }
        float cv = cst[0];
        float4 s;
        s.x = fmaxf(sum.x + cv, 0.f);
        s.y = fmaxf(sum.y + cv, 0.f);
        s.z = fmaxf(sum.z + cv, 0.f);
        s.w = fmaxf(sum.w + cv, 0.f);
        s_s[tid] = s;
    }
    __syncthreads();
    float4 sv = s_s[i4l];
    #pragma unroll
    for (int j = 0; j < 8; j++) {
        int c = cg * 8 + j;
        float g  = g_s[c];
        float be = be_s[c];
        float4 xv = xc[j];
        float4 o;
        o.x = fmaf(sv.x, g, xv.x) + be;
        o.y = fmaf(sv.y, g, xv.y) + be;
        o.z = fmaf(sv.z, g, xv.z) + be;
        o.w = fmaf(sv.w, g, xv.w) + be;
        o4[(size_t)c * NN4 + i4l] = o;
    }
}

extern "C" void kernel_launch(void* const* d_in, const int* in_sizes, int n_in,
                              void* d_out, int out_size, void* d_ws, size_t ws_size,
                              hipStream_t stream) {
    const float* x    = (const float*)d_in[0];
    const float* Wq   = (const float*)d_in[1];
    const float* bq   = (const float*)d_in[2];
    const float* Wk   = (const float*)d_in[3];
    const float* bk   = (const float*)d_in[4];
    const float* Wv   = (const float*)d_in[5];
    const float* bv   = (const float*)d_in[6];
    const float* Wcat = (const float*)d_in[7];
    const float* Wexp = (const float*)d_in[8];
    const float* bexp = (const float*)d_in[9];
    float* out = (float*)d_out;

    float* ws   = (float*)d_ws;
    float* xbar = ws;                 // 2048
    float* gexp = ws + 2048;          // 2048
    float* A    = ws + 4096;          // 256
    float* cst  = ws + 4352;          // 1 (+pad)
    float* hg   = ws + 4368;          // 256
    float* Mg   = ws + 4624;          // 65536

    k1<<<BB * CC + CC + 1, 256, 0, stream>>>(x, Wq, bq, Wk, bk, Wv, bv, Wcat, Wexp,
                                             xbar, Mg, hg, A, cst);
    k2<<<512, 256, 0, stream>>>(xbar, Mg, hg, gexp);
    k3<<<BB * NTILES, 256, 0, stream>>>(x, A, cst, gexp, bexp, out);
}